// Round 13
// baseline (258.304 us; speedup 1.0000x reference)
//
#include <hip/hip_runtime.h>
#include <hip/hip_bf16.h>

#define BB 4
#define NN 2048
#define FIN 32
#define TT 16
#define EE 32768
#define CC 64
#define TFo 64
#define NSPLIT 8

typedef __attribute__((ext_vector_type(8))) short bf16x8;
typedef __attribute__((ext_vector_type(4))) float f32x4;

typedef __attribute__((address_space(1))) const unsigned int as1_uint;
typedef __attribute__((address_space(3))) unsigned int as3_uint;

__device__ __forceinline__ void gload_lds16(const void* g, void* l) {
    __builtin_amdgcn_global_load_lds((as1_uint*)g, (as3_uint*)l, 16, 0, 0);
}

__device__ __forceinline__ unsigned short f2bf(float v) {
    unsigned u = __builtin_bit_cast(unsigned, v);
    unsigned r = (u + 0x7fffu + ((u >> 16) & 1u)) >> 16;
    return (unsigned short)r;
}

__device__ __forceinline__ float bf2f(unsigned short v) {
    return __builtin_bit_cast(float, (unsigned)v << 16);
}

// ---------------- Stage A: temporal attention ----------------

__global__ void k_xreduce(const float* __restrict__ X, const float* __restrict__ U1,
                          const float* __restrict__ U3,
                          float* __restrict__ tmp1, float* __restrict__ rhs) {
    int b = blockIdx.x >> 6;
    int n0 = (blockIdx.x & 63) * 32;
    int tid = threadIdx.x;
    int w = tid >> 6, lane = tid & 63;
    float u3a = U3[tid >> 4];
    float u3b = U3[(tid >> 4) + 16];
    __shared__ float part[32][4][16];
    float a0 = 0.f, a1 = 0.f;
    for (int i = 0; i < 32; ++i) {
        int n = n0 + i;
        float u = U1[n];
        const float* rowp = X + ((size_t)(b * NN + n)) * 512;
        float x0 = rowp[tid], x1 = rowp[tid + 256];
        a0 += u * x0; a1 += u * x1;
        float c = u3a * x0 + u3b * x1;
        c += __shfl_xor(c, 16);
        c += __shfl_xor(c, 32);
        if (lane < 16) part[i][w][lane] = c;
    }
    atomicAdd(&tmp1[b * 512 + tid], a0);
    atomicAdd(&tmp1[b * 512 + tid + 256], a1);
    __syncthreads();
#pragma unroll
    for (int q = 0; q < 2; ++q) {
        int idx = tid + q * 256;
        int i = idx >> 4, tt = idx & 15;
        float s = part[i][0][tt] + part[i][1][tt] + part[i][2][tt] + part[i][3][tt];
        rhs[((size_t)(b * NN + n0 + i)) * 16 + tt] = s;
    }
}

// fused mklhs + ptaccum: lhs computed in LDS, never hits HBM (Pt pre-zeroed)
__global__ void k_lhspt(const float* __restrict__ tmp1, const float* __restrict__ U2,
                        const float* __restrict__ rhs, float* __restrict__ Pt) {
    int b = blockIdx.x >> 5;
    int n0 = (blockIdx.x & 31) * 64;
    int tid = threadIdx.x;
    __shared__ float t1[512];
    __shared__ float lhsl[16][65];
    t1[tid] = tmp1[b * 512 + tid];
    t1[tid + 256] = tmp1[b * 512 + tid + 256];
    __syncthreads();
#pragma unroll
    for (int q = 0; q < 4; ++q) {
        int idx = tid + q * 256;
        int t = idx >> 6, nl = idx & 63;
        float acc = 0.f;
#pragma unroll
        for (int f = 0; f < 32; ++f) acc += t1[f * 16 + t] * U2[f * NN + n0 + nl];
        lhsl[t][nl] = acc;
    }
    __syncthreads();
    int t = tid >> 4, s = tid & 15;
    const float* rr = rhs + (size_t)b * NN * TT;
    float acc = 0.f;
    for (int i = 0; i < 64; ++i) acc += lhsl[t][i] * rr[(n0 + i) * 16 + s];
    atomicAdd(&Pt[b * 256 + tid], acc);
}

__global__ void k_temporalatt(const float* __restrict__ Pt, const float* __restrict__ be,
                              const float* __restrict__ Ve, float* __restrict__ Emat) {
    int b = blockIdx.x;
    int t = threadIdx.x >> 4, s = threadIdx.x & 15;
    __shared__ float sg[16][17];
    __shared__ float em[16][17];
    float v = Pt[b * 256 + t * 16 + s] + be[t * 16 + s];
    sg[t][s] = 1.f / (1.f + __expf(-v));
    __syncthreads();
    float e = 0.f;
#pragma unroll
    for (int u = 0; u < 16; ++u) e += Ve[t * 16 + u] * sg[u][s];
    em[t][s] = e;
    __syncthreads();
    float mx = -1e30f;
#pragma unroll
    for (int u = 0; u < 16; ++u) mx = fmaxf(mx, em[u][s]);
    float sum = 0.f;
#pragma unroll
    for (int u = 0; u < 16; ++u) sum += __expf(em[u][s] - mx);
    Emat[b * 256 + t * 16 + s] = __expf(e - mx) / sum;
}

// ---------------- Stage B: spatial attention (applyemat fused in) ----------------

__global__ void k_spatiallr(const float* __restrict__ X, const float* __restrict__ Emat,
                            const float* __restrict__ W1, const float* __restrict__ W2,
                            const float* __restrict__ W3,
                            float* __restrict__ lhs_s, float* __restrict__ rhs_s) {
    int b = blockIdx.x >> 7;
    int n0 = (blockIdx.x & 127) * 16;
    __shared__ float em[256];
    __shared__ float xb[16 * 32 * 17];   // Xt, [(nl*32+f)*17 + s]
    __shared__ float av[16 * 32];
    em[threadIdx.x] = Emat[b * 256 + threadIdx.x];
    __syncthreads();
#pragma unroll
    for (int ii = 0; ii < 2; ++ii) {
        int p = threadIdx.x * 2 + ii;    // nl*32 + f
        int nl = p >> 5, f = p & 31;
        const float4* src = (const float4*)(X + ((size_t)(b * NN + n0 + nl)) * 512 + f * 16);
        float4 q0 = src[0], q1 = src[1], q2 = src[2], q3 = src[3];
        float xv[16] = {q0.x, q0.y, q0.z, q0.w, q1.x, q1.y, q1.z, q1.w,
                        q2.x, q2.y, q2.z, q2.w, q3.x, q3.y, q3.z, q3.w};
        float o[16];
#pragma unroll
        for (int s = 0; s < 16; ++s) o[s] = 0.f;
#pragma unroll
        for (int t = 0; t < 16; ++t) {
            float xt = xv[t];
            const float* er = &em[t * 16];
#pragma unroll
            for (int s = 0; s < 16; ++s) o[s] += xt * er[s];
        }
        float a = 0.f;
#pragma unroll
        for (int s = 0; s < 16; ++s) { xb[p * 17 + s] = o[s]; a += o[s] * W1[s]; }
        av[p] = a;
    }
    __syncthreads();
    int nl = threadIdx.x >> 4, t = threadIdx.x & 15;
    float r = 0.f;
#pragma unroll
    for (int f = 0; f < 32; ++f) r += W3[f] * xb[(nl * 32 + f) * 17 + t];
    rhs_s[(size_t)b * TT * NN + (size_t)t * NN + n0 + nl] = r;
    float l = 0.f;
#pragma unroll
    for (int f = 0; f < 32; ++f) l += av[nl * 32 + f] * W2[f * 16 + t];
    lhs_s[((size_t)(b * NN + n0 + nl)) * 16 + t] = l;
}

// ---------------- fused prep: Vs->bf16 (vectorized) + MFMA A-fragment build ----------
__global__ void k_prep(const float* __restrict__ Vs, unsigned short* __restrict__ Vsbf,
                       const float* __restrict__ cW, const float* __restrict__ Wt,
                       const float* __restrict__ Wr, const float* __restrict__ bt,
                       const float* __restrict__ br,
                       unsigned short* __restrict__ WAcheb,
                       unsigned short* __restrict__ WAtc,
                       unsigned short* __restrict__ WAres,
                       float* __restrict__ btr) {
    int i = blockIdx.x * 256 + threadIdx.x;
    {
        float4 v = *((const float4*)Vs + i);
        ushort4 o;
        o.x = f2bf(v.x); o.y = f2bf(v.y); o.z = f2bf(v.z); o.w = f2bf(v.w);
        *((ushort4*)Vsbf + i) = o;
    }
    int idx = i;
    if (idx < 6144) {                      // cheb
        int j = idx & 7, l = (idx >> 3) & 63, fi = idx >> 9;   // fi = ks*4+i
        int row = ((fi & 3) << 4) + (l & 15);
        int kidx = ((fi >> 2) << 5) + ((l >> 4) << 3) + j;
        int k = kidx >> 5, f = kidx & 31;
        WAcheb[idx] = f2bf(cW[k * 2048 + f * 64 + row]);
    } else if (idx < 18432) {              // temporal conv
        int e = idx - 6144;
        int j = e & 7, l = (e >> 3) & 63, fi = e >> 9;         // fi = ks*4+i, ks<6
        int row = ((fi & 3) << 4) + (l & 15);
        int kidx = ((fi >> 2) << 5) + ((l >> 4) << 3) + j;
        int tap = kidx >> 6, c = kidx & 63;
        WAtc[e] = f2bf(Wt[row * 192 + c * 3 + tap]);
    } else if (idx < 20480) {              // residual
        int e = idx - 18432;
        int j = e & 7, l = (e >> 3) & 63, q = e >> 9;
        int row = (q << 4) + (l & 15);
        int f = ((l >> 4) << 3) + j;
        WAres[e] = f2bf(Wr[row * 32 + f]);
    } else if (idx < 20544) {
        int o = idx - 20480;
        btr[o] = bt[o] + br[o];
    }
}

// sigT[b][k][m] = bf16(sigmoid(dot(lhs_s[b,m,:], rhs_s[b,:,k]) + bs[m,k]))
__global__ void k_makesigT(const float* __restrict__ lhs_s, const float* __restrict__ rhs_s,
                           const float* __restrict__ bs, unsigned short* __restrict__ sigT) {
    int k0 = blockIdx.x * 64, m0 = blockIdx.y * 64;
    __shared__ float lh[64][17];
    __shared__ float rh[16][64];
    __shared__ float bsl[64][65];
    int tid = threadIdx.x;
#pragma unroll
    for (int i = 0; i < 16; ++i) {
        int idx = tid + i * 256;
        int mi = idx >> 6, kj = idx & 63;
        bsl[mi][kj] = bs[(size_t)(m0 + mi) * NN + k0 + kj];
    }
    int ml = tid & 63;
    int kg = (tid >> 6) * 16;
    for (int b = 0; b < BB; ++b) {
        __syncthreads();
#pragma unroll
        for (int i = 0; i < 4; ++i) {
            int idx = tid + i * 256;
            int mi = idx >> 4, t = idx & 15;
            lh[mi][t] = lhs_s[((size_t)(b * NN + m0 + mi)) * 16 + t];
            int tt = idx >> 6, kj = idx & 63;
            rh[tt][kj] = rhs_s[(size_t)b * TT * NN + (size_t)tt * NN + k0 + kj];
        }
        __syncthreads();
        unsigned short* out = sigT + (size_t)b * NN * NN;
#pragma unroll 4
        for (int ki = 0; ki < 16; ++ki) {
            int kl = kg + ki;
            float acc = bsl[ml][kl];
#pragma unroll
            for (int t = 0; t < 16; ++t) acc += lh[ml][t] * rh[t][kl];
            float sgv = 1.f / (1.f + __expf(-acc));
            out[(size_t)(k0 + kl) * NN + m0 + ml] = f2bf(sgv);
        }
    }
}

// ---------------- big GEMM: 256x256, BK=64, half-tile ring pipeline (T3+T4+T5) --------
// LDS = ring of 4 slots (one K-half each: A 256x32 + B 256x32 = 32KB). 64 phases;
// phase h computes slot h&3 while staging half h+3 into slot (h+3)&3 (freed at h-1).
// Swizzle: 16B-group kg ^= (row>>1)&3  (2-way = free). vmcnt(12) steady state.
__global__ __launch_bounds__(512, 2) void k_gemm256(const unsigned short* __restrict__ A,
                                                    const unsigned short* __restrict__ Bt,
                                                    float* __restrict__ C,
                                                    float* __restrict__ pm,
                                                    float* __restrict__ ps) {
    __shared__ __align__(16) unsigned short ldsS[4][16384];   // 128 KB ring
    const int tid = threadIdx.x;
    const int wid = tid >> 6, lane = tid & 63;
    const int wrM = (wid >> 2) << 7;     // 0 / 128
    const int wcN = (wid & 3) << 6;      // 0..192
    const int rl = lane & 15;
    const int kg16 = lane >> 4;          // 16B-group within K-half
    const int bm = blockIdx.y << 8;
    const int bn = blockIdx.x << 8;
    const int b = blockIdx.z;
    const unsigned short* Bb = Bt + (size_t)b * NN * NN;
    float* Cb = C + (size_t)b * NN * NN;

    f32x4 acc[8][4];
#pragma unroll
    for (int i = 0; i < 8; ++i)
#pragma unroll
        for (int j = 0; j < 4; ++j) acc[i][j] = (f32x4){0.f, 0.f, 0.f, 0.f};

    // stage one K-half (A 256x32 + B 256x32) into slot (hh)&3; 4 gloads/thread
#define STAGEH(hh)                                                                  \
    {                                                                               \
        int slot_ = (hh) & 3;                                                       \
        int koff_ = (hh) << 5;                                                      \
        _Pragma("unroll")                                                           \
        for (int q = 0; q < 2; ++q) {                                               \
            int L_ = (q << 9) + tid;                                                \
            int row_ = L_ >> 2;                                                     \
            int ksw_ = (L_ & 3) ^ ((row_ >> 1) & 3);                                \
            gload_lds16(A + (size_t)(bm + row_) * NN + koff_ + (ksw_ << 3),         \
                        &ldsS[slot_][((q << 9) + (wid << 6)) << 3]);                \
            gload_lds16(Bb + (size_t)(bn + row_) * NN + koff_ + (ksw_ << 3),        \
                        &ldsS[slot_][8192 + (((q << 9) + (wid << 6)) << 3)]);       \
        }                                                                           \
    }

    const int NPH = (NN >> 5);   // 64 half-phases
    STAGEH(0)
    STAGEH(1)
    STAGEH(2)
    for (int h = 0; h < NPH; ++h) {
        if (h < NPH - 3) {
            STAGEH(h + 3)
            asm volatile("s_waitcnt vmcnt(12)" ::: "memory");
        } else if (h == NPH - 3) {
            asm volatile("s_waitcnt vmcnt(8)" ::: "memory");
        } else if (h == NPH - 2) {
            asm volatile("s_waitcnt vmcnt(4)" ::: "memory");
        } else {
            asm volatile("s_waitcnt vmcnt(0)" ::: "memory");
        }
        asm volatile("s_barrier" ::: "memory");   // slot h&3 ready for all waves
        {
            const unsigned short* sl = &ldsS[h & 3][0];
            bf16x8 af[8], bfr[4];
#pragma unroll
            for (int i = 0; i < 8; ++i) {
                int r = wrM + (i << 4) + rl;
                af[i] = *(const bf16x8*)(sl + (r << 5) + ((kg16 ^ ((r >> 1) & 3)) << 3));
            }
#pragma unroll
            for (int j = 0; j < 4; ++j) {
                int r = wcN + (j << 4) + rl;
                bfr[j] = *(const bf16x8*)(sl + 8192 + (r << 5) + ((kg16 ^ ((r >> 1) & 3)) << 3));
            }
            __builtin_amdgcn_s_setprio(1);
#pragma unroll
            for (int i = 0; i < 8; ++i)
#pragma unroll
                for (int j = 0; j < 4; ++j)
                    acc[i][j] = __builtin_amdgcn_mfma_f32_16x16x32_bf16(af[i], bfr[j], acc[i][j], 0, 0, 0);
            __builtin_amdgcn_s_setprio(0);
        }
        asm volatile("s_barrier" ::: "memory");   // all reads of slot h&3 done
    }
#undef STAGEH

    // ---- C write ----
    const int cl = lane & 15, rg = (lane >> 4) << 2;
#pragma unroll
    for (int i = 0; i < 8; ++i)
#pragma unroll
        for (int j = 0; j < 4; ++j) {
            int m0 = bm + wrM + (i << 4) + rg;
            int n0 = bn + wcN + (j << 4) + cl;
#pragma unroll
            for (int r = 0; r < 4; ++r) Cb[(size_t)(m0 + r) * NN + n0] = acc[i][j][r];
        }

    // ---- fused column-softmax partials over this block's 256 rows ----
    float* smax = (float*)&ldsS[0][0];
    float* ssum = smax + 512;
#pragma unroll
    for (int j = 0; j < 4; ++j) {
        float mx = -1e30f;
#pragma unroll
        for (int i = 0; i < 8; ++i)
#pragma unroll
            for (int r = 0; r < 4; ++r) mx = fmaxf(mx, acc[i][j][r]);
        float se = 0.f;
#pragma unroll
        for (int i = 0; i < 8; ++i)
#pragma unroll
            for (int r = 0; r < 4; ++r) se += __expf(acc[i][j][r] - mx);
#pragma unroll
        for (int m = 16; m <= 32; m <<= 1) {
            float omx = __shfl_xor(mx, m);
            float ose = __shfl_xor(se, m);
            float nm = fmaxf(mx, omx);
            se = se * __expf(mx - nm) + ose * __expf(omx - nm);
            mx = nm;
        }
        if (lane < 16) {
            int idx = wcN + (j << 4) + lane;
            smax[((wid >> 2) << 8) + idx] = mx;
            ssum[((wid >> 2) << 8) + idx] = se;
        }
    }
    __syncthreads();
    if (tid < 256) {
        float m0 = smax[tid], m1 = smax[256 + tid];
        float s0 = ssum[tid], s1 = ssum[256 + tid];
        float nm = fmaxf(m0, m1);
        float s = s0 * __expf(m0 - nm) + s1 * __expf(m1 - nm);
        size_t o = ((size_t)(b * NSPLIT + blockIdx.y) * NN) + bn + tid;
        pm[o] = nm;
        ps[o] = s;
    }
}

// combine NSPLIT partials -> Mf[b][k], Inv[b][k]
__global__ void k_colreduce2(const float* __restrict__ pm, const float* __restrict__ ps,
                             float* __restrict__ Mf, float* __restrict__ Inv) {
    int idx = blockIdx.x * 256 + threadIdx.x;
    float M = -1e30f, Ssum = 0.f;
#pragma unroll
    for (int i = 0; i < NSPLIT; ++i) {
        size_t o = ((size_t)((idx >> 11) * NSPLIT + i) * NN) + (idx & (NN - 1));
        float mm = pm[o], sv = ps[o];
        float nm = fmaxf(M, mm);
        Ssum = Ssum * __expf(M - nm) + sv * __expf(mm - nm);
        M = nm;
    }
    Mf[idx] = M;
    Inv[idx] = 1.f / Ssum;
}

__global__ void k_diagatt(const float* __restrict__ S, const int* __restrict__ row,
                          const int* __restrict__ col, const float* __restrict__ norm,
                          const float* __restrict__ Mf, const float* __restrict__ Inv,
                          float* __restrict__ diagS, float* __restrict__ att) {
    int idx = blockIdx.x * 256 + threadIdx.x;
    if (idx < BB * EE) {
        int b = idx >> 15, e = idx & (EE - 1);
        int c = col[e];
        float v = S[(size_t)b * NN * NN + (size_t)row[e] * NN + c];
        att[idx] = norm[e] * __expf(v - Mf[b * NN + c]) * Inv[b * NN + c];
    }
    if (idx < BB * NN) {
        float v = S[(size_t)(idx >> 11) * NN * NN + (size_t)(idx & (NN - 1)) * NN + (idx & (NN - 1))];
        diagS[idx] = __expf(v - Mf[idx]) * Inv[idx];
    }
}

// ---------------- graph prep ----------------

__global__ void k_deg(const int* __restrict__ row, const int* __restrict__ col,
                      float* __restrict__ deg, int* __restrict__ cnt) {
    int e = blockIdx.x * 256 + threadIdx.x;
    if (e < EE) {
        int r = row[e];
        if (r != col[e]) atomicAdd(&deg[r], 1.0f);
        atomicAdd(&cnt[r], 1);
    }
}

__global__ void k_dinv(const float* __restrict__ deg, float* __restrict__ dinv) {
    int n = blockIdx.x * 256 + threadIdx.x;
    if (n < NN) {
        float d = deg[n];
        dinv[n] = d > 0.f ? rsqrtf(fmaxf(d, 1e-12f)) : 0.f;
    }
}

__global__ void k_scan(const int* __restrict__ cnt, int* __restrict__ starts) {
    __shared__ int part[256];
    int t = threadIdx.x;
    int loc[8];
    int s = 0;
#pragma unroll
    for (int i = 0; i < 8; ++i) {
        int c = cnt[t * 8 + i];
        loc[i] = s;
        s += c;
    }
    part[t] = s;
    __syncthreads();
    for (int o = 1; o < 256; o <<= 1) {
        int v = (t >= o) ? part[t - o] : 0;
        __syncthreads();
        part[t] += v;
        __syncthreads();
    }
    int pbase = (t > 0) ? part[t - 1] : 0;
#pragma unroll
    for (int i = 0; i < 8; ++i) starts[t * 8 + i] = pbase + loc[i];
    if (t == 255) starts[NN] = part[255];
}

__global__ void k_scatter(const int* __restrict__ row, const int* __restrict__ col,
                          const float* __restrict__ dinv, const int* __restrict__ starts,
                          int* __restrict__ cursor, int* __restrict__ eid,
                          float* __restrict__ norm) {
    int e = blockIdx.x * 256 + threadIdx.x;
    if (e < EE) {
        int r = row[e], c = col[e];
        float w = (r != c) ? 1.f : 0.f;
        norm[e] = -dinv[r] * w * dinv[c];
        int slot = atomicAdd(&cursor[r], 1);
        eid[starts[r] + slot] = e;
    }
}

// ---------------- Chebyshev (bf16 TRANSPOSED [t][f] pipeline) ----------------

__global__ void k_tx0T(const float* __restrict__ X, const float* __restrict__ diagS,
                       unsigned short* __restrict__ Tx0T, unsigned short* __restrict__ XbfT) {
    int j = threadIdx.x >> 6, l = threadIdx.x & 63;
    int bn = (blockIdx.x << 2) + j;
    __shared__ float lt[4][16][33];
    float d = diagS[bn];
    const float* xp = X + (size_t)bn * 512;
    {
        int f = l >> 1, t0 = (l & 1) << 3;
        float4 a = *(const float4*)(xp + f * 16 + t0);
        float4 b4 = *(const float4*)(xp + f * 16 + t0 + 4);
        lt[j][t0 + 0][f] = a.x;  lt[j][t0 + 1][f] = a.y;
        lt[j][t0 + 2][f] = a.z;  lt[j][t0 + 3][f] = a.w;
        lt[j][t0 + 4][f] = b4.x; lt[j][t0 + 5][f] = b4.y;
        lt[j][t0 + 6][f] = b4.z; lt[j][t0 + 7][f] = b4.w;
    }
    __syncthreads();
    int t = l >> 2, f0 = (l & 3) << 3;
    unsigned ox[4], otx[4];
#pragma unroll
    for (int i = 0; i < 4; ++i) {
        float v0 = lt[j][t][f0 + 2 * i];
        float v1 = lt[j][t][f0 + 2 * i + 1];
        ox[i] = (unsigned)f2bf(v0) | ((unsigned)f2bf(v1) << 16);
        otx[i] = (unsigned)f2bf(v0 * d) | ((unsigned)f2bf(v1 * d) << 16);
    }
    size_t o = (size_t)bn * 512 + t * 32 + f0;
    *(uint4*)(XbfT + o) = make_uint4(ox[0], ox[1], ox[2], ox[3]);
    *(uint4*)(Tx0T + o) = make_uint4(otx[0], otx[1], otx[2], otx[3]);
}

__global__ void k_prop(const unsigned short* __restrict__ x, const float* __restrict__ att,
                       const int* __restrict__ col, const int* __restrict__ starts,
                       const int* __restrict__ eid, const unsigned short* __restrict__ sub,
                       unsigned short* __restrict__ out, int mode) {
    int g = threadIdx.x >> 7;
    int l = threadIdx.x & 127;
    int bn = (blockIdx.x << 1) + g;
    int b = bn >> 11, n = bn & (NN - 1);
    int s0 = starts[n], s1 = starts[n + 1];
    const unsigned short* xb = x + (size_t)b * NN * 512;
    const float* attb = att + (size_t)b * EE;
    float ax = 0.f, ay = 0.f, az = 0.f, aw = 0.f;
    float bx = 0.f, by = 0.f, bz = 0.f, bw = 0.f;
    int jj = s0;
    for (; jj + 2 <= s1; jj += 2) {
        int e0 = eid[jj], e1 = eid[jj + 1];
        float a0 = attb[e0], a1 = attb[e1];
        ushort4 v0 = *((const ushort4*)(xb + (size_t)col[e0] * 512) + l);
        ushort4 v1 = *((const ushort4*)(xb + (size_t)col[e1] * 512) + l);
        ax += a0 * bf2f(v0.x); ay += a0 * bf2f(v0.y); az += a0 * bf2f(v0.z); aw += a0 * bf2f(v0.w);
        bx += a1 * bf2f(v1.x); by += a1 * bf2f(v1.y); bz += a1 * bf2f(v1.z); bw += a1 * bf2f(v1.w);
    }
    if (jj < s1) {
        int e0 = eid[jj];
        float a0 = attb[e0];
        ushort4 v0 = *((const ushort4*)(xb + (size_t)col[e0] * 512) + l);
        ax += a0 * bf2f(v0.x); ay += a0 * bf2f(v0.y); az += a0 * bf2f(v0.z); aw += a0 * bf2f(v0.w);
    }
    float rx = ax + bx, ry = ay + by, rz = az + bz, rw = aw + bw;
    size_t o = (size_t)bn * 512 + (l << 2);
    if (mode) {
        ushort4 sv = *(const ushort4*)(sub + o);
        rx = 2.f * rx - bf2f(sv.x); ry = 2.f * ry - bf2f(sv.y);
        rz = 2.f * rz - bf2f(sv.z); rw = 2.f * rw - bf2f(sv.w);
    }
    ushort4 ov;
    ov.x = f2bf(rx); ov.y = f2bf(ry); ov.z = f2bf(rz); ov.w = f2bf(rw);
    *(ushort4*)(out + o) = ov;
}

// ---------------- fused cheb + temporal conv + residual + LN via MFMA ----------------
#define XHP2 72
__global__ __launch_bounds__(64) void k_chebfinal(
    const unsigned short* __restrict__ Tx0T, const unsigned short* __restrict__ Tx1T,
    const unsigned short* __restrict__ Tx2T, const unsigned short* __restrict__ XbfT,
    const unsigned short* __restrict__ WAcheb,
    const unsigned short* __restrict__ WAtc,
    const unsigned short* __restrict__ WAres,
    const float* __restrict__ cb, const float* __restrict__ btr,
    const float* __restrict__ gamma, const float* __restrict__ beta,
    float* __restrict__ out) {
    int l = threadIdx.x;
    int bn = blockIdx.x;
    int tl = l & 15, fg = l >> 4;
    __shared__ unsigned short xhT[18 * XHP2];
    xhT[l] = 0;
    xhT[17 * XHP2 + l] = 0;
    size_t fo = (size_t)bn * 512 + tl * 32 + fg * 8;
    bf16x8 bT0 = *(const bf16x8*)(Tx0T + fo);
    bf16x8 bT1 = *(const bf16x8*)(Tx1T + fo);
    bf16x8 bT2 = *(const bf16x8*)(Tx2T + fo);
    bf16x8 bX = *(const bf16x8*)(XbfT + fo);

    // --- cheb ---
    f32x4 acc[4];
#pragma unroll
    for (int i = 0; i < 4; ++i) acc[i] = (f32x4){0.f, 0.f, 0.f, 0.f};
#pragma unroll
    for (int ks = 0; ks < 3; ++ks) {
        bf16x8 bfrag = (ks == 0) ? bT0 : (ks == 1) ? bT1 : bT2;
#pragma unroll
        for (int i = 0; i < 4; ++i)
            acc[i] = __builtin_amdgcn_mfma_f32_16x16x32_bf16(
                *(const bf16x8*)&WAcheb[((ks * 4 + i) * 64 + l) * 8], bfrag, acc[i], 0, 0, 0);
    }
#pragma unroll
    for (int i = 0; i < 4; ++i) {
        int cbase = i * 16 + fg * 4;
        float4 cv = *(const float4*)&cb[cbase];
        float h0 = fmaxf(acc[i][0] + cv.x, 0.f);
        float h1 = fmaxf(acc[i][1] + cv.y, 0.f);
        float h2v = fmaxf(acc[i][2] + cv.z, 0.f);
        float h3 = fmaxf(acc[i][3] + cv.w, 0.f);
        unsigned lo = (unsigned)f2bf(h0) | ((unsigned)f2bf(h1) << 16);
        unsigned hi = (unsigned)f2bf(h2v) | ((unsigned)f2bf(h3) << 16);
        *(uint2*)&xhT[(tl + 1) * XHP2 + cbase] = make_uint2(lo, hi);
    }
    __syncthreads();

    // --- temporal conv + residual ---
    f32x4 a2[4];
#pragma unroll
    for (int i = 0; i < 4; ++i) a2[i] = (f32x4){0.f, 0.f, 0.f, 0.f};
#pragma unroll
    for (int ks = 0; ks < 6; ++ks) {
        int kb = ks * 32 + fg * 8;
        bf16x8 bfrag = *(const bf16x8*)&xhT[(tl + (kb >> 6)) * XHP2 + (kb & 63)];
#pragma unroll
        for (int i = 0; i < 4; ++i)
            a2[i] = __builtin_amdgcn_mfma_f32_16x16x32_bf16(
                *(const bf16x8*)&WAtc[((ks * 4 + i) * 64 + l) * 8], bfrag, a2[i], 0, 0, 0);
    }
#pragma unroll
    for (int i = 0; i < 4; ++i)
        a2[i] = __builtin_amdgcn_mfma_f32_16x16x32_bf16(
            *(const bf16x8*)&WAres[(i * 64 + l) * 8], bX, a2[i], 0, 0, 0);

    float h2[16];
#pragma unroll
    for (int i = 0; i < 4; ++i) {
        float4 bv = *(const float4*)&btr[i * 16 + fg * 4];
        h2[i * 4 + 0] = fmaxf(a2[i][0] + bv.x, 0.f);
        h2[i * 4 + 1] = fmaxf(a2[i][1] + bv.y, 0.f);
        h2[i * 4 + 2] = fmaxf(a2[i][2] + bv.z, 0.f);
        h2[i * 4 + 3] = fmaxf(a2[i][3] + bv.w, 0.f);
    }
    float s1 = 0.f, s2 = 0.f;
#pragma unroll
    for (int q = 0; q < 16; ++q) { s1 += h2[q]; s2 += h2[q] * h2[q]; }
    s1 += __shfl_xor(s1, 16); s2 += __shfl_xor(s2, 16);
    s1 += __shfl_xor(s1, 32); s2 += __shfl_xor(s2, 32);
    float mu = s1 * (1.f / 64.f);
    float rs = rsqrtf(s2 * (1.f / 64.f) - mu * mu + 1e-5f);
    float* ob = out + (size_t)bn * 1024 + tl;
#pragma unroll
    for (int i = 0; i < 4; ++i) {
        int cbase = i * 16 + fg * 4;
        float4 gv = *(const float4*)&gamma[cbase];
        float4 bv = *(const float4*)&beta[cbase];
        ob[(cbase + 0) * 16] = (h2[i * 4 + 0] - mu) * rs * gv.x + bv.x;
        ob[(cbase + 1) * 16] = (h2[i * 4 + 1] - mu) * rs * gv.y + bv.y;
        ob[(cbase + 2) * 16] = (h2[i * 4 + 2] - mu) * rs * gv.z + bv.z;
        ob[(cbase + 3) * 16] = (h2[i * 4 + 3] - mu) * rs * gv.w + bv.w;
    }
}

// ---------------- host ----------------

extern "C" void kernel_launch(void* const* d_in, const int* in_sizes, int n_in,
                              void* d_out, int out_size, void* d_ws, size_t ws_size,
                              hipStream_t stream) {
    (void)in_sizes; (void)n_in; (void)out_size; (void)ws_size;
    const float* X = (const float*)d_in[0];
    const int* ei = (const int*)d_in[1];
    const int* row = ei;
    const int* col = ei + EE;
    const float* U1 = (const float*)d_in[2];
    const float* U2 = (const float*)d_in[3];
    const float* U3 = (const float*)d_in[4];
    const float* be = (const float*)d_in[5];
    const float* Ve = (const float*)d_in[6];
    const float* W1 = (const float*)d_in[7];
    const float* W2 = (const float*)d_in[8];
    const float* W3 = (const float*)d_in[9];
    const float* bs = (const float*)d_in[10];
    const float* Vs = (const float*)d_in[11];
    const float* cW = (const float*)d_in[12];
    const float* cb = (const float*)d_in[13];
    const float* Wt = (const float*)d_in[14];
    const float* bt = (const float*)d_in[15];
    const float* Wr = (const float*)d_in[16];
    const float* br = (const float*)d_in[17];
    const float* gamma = (const float*)d_in[18];
    const float* beta = (const float*)d_in[19];
    float* out = (float*)d_out;

    char* w = (char*)d_ws;
    constexpr size_t OFF_TMP1 = 0;            // 8192
    constexpr size_t OFF_PT = 8192;           // 4096
    constexpr size_t OFF_DEG = 12288;         // 8192
    constexpr size_t OFF_CNT = 20480;         // 8192
    constexpr size_t OFF_CURSOR = 28672;      // 8192
    constexpr size_t ZEND = 36864;
    constexpr size_t OFF_EMAT = ZEND;                     // 4096
    constexpr size_t OFF_LHS = OFF_EMAT + 4096;           // 512K (unused now)
    constexpr size_t OFF_RHS = OFF_LHS + 524288;          // 512K
    constexpr size_t OFF_LHSS = OFF_RHS + 524288;         // 512K (reused: pm)
    constexpr size_t OFF_RHSS = OFF_LHSS + 524288;        // 512K (reused: ps)
    constexpr size_t OFF_DIAG = OFF_RHSS + 524288;        // 32K
    constexpr size_t OFF_ATT = OFF_DIAG + 32768;          // 512K
    constexpr size_t OFF_DINV = OFF_ATT + 524288;         // 8K
    constexpr size_t OFF_NORM = OFF_DINV + 8192;          // 128K
    constexpr size_t OFF_STARTS = OFF_NORM + 131072;      // 8448
    constexpr size_t OFF_EID = OFF_STARTS + 8448;         // 128K
    constexpr size_t OFF_WA = OFF_EID + 131072;           // 56K region for frags
    constexpr size_t OFF_WACHEB = OFF_WA;                 // 12288
    constexpr size_t OFF_WATC = OFF_WA + 12288;           // 24576
    constexpr size_t OFF_WARES = OFF_WA + 36864;          // 4096
    constexpr size_t OFF_BTR = OFF_WA + 40960;            // 256
    constexpr size_t OFF_VSBF = OFF_WA + 57344;           // 8MB (reused: Mf/Inv)
    constexpr size_t OFF_TX0 = OFF_VSBF + 8388608;        // 8.4MB Tx0T + 8.4MB XbfT
    constexpr size_t OFF_XBF = OFF_TX0 + 8388608;
    constexpr size_t OFF_SIGT = OFF_XBF + 8388608;        // 32MB
    constexpr size_t OFF_S = OFF_SIGT + 33554432;         // 64MB (reused: Tx1, Tx2 bf16)

    float* tmp1 = (float*)(w + OFF_TMP1);
    float* Pt = (float*)(w + OFF_PT);
    float* deg = (float*)(w + OFF_DEG);
    int* cnt = (int*)(w + OFF_CNT);
    int* cursor = (int*)(w + OFF_CURSOR);
    float* Emat = (float*)(w + OFF_EMAT);
    float* rhs = (float*)(w + OFF_RHS);
    float* lhs_s = (float*)(w + OFF_LHSS);
    float* rhs_s = (float*)(w + OFF_RHSS);
    float* diagS = (float*)(w + OFF_DIAG);
    float* att = (float*)(w + OFF_ATT);
    float* dinv = (float*)(w + OFF_DINV);
    float* normv = (float*)(w + OFF_NORM);
    int* starts = (int*)(w + OFF_STARTS);
    int* eid = (int*)(w + OFF_EID);
    unsigned short* WAcheb = (unsigned short*)(w + OFF_WACHEB);
    unsigned short* WAtc = (unsigned short*)(w + OFF_WATC);
    unsigned short* WAres = (unsigned short*)(w + OFF_WARES);
    float* btr = (float*)(w + OFF_BTR);
    unsigned short* Vsbf = (unsigned short*)(w + OFF_VSBF);
    float* pm = (float*)(w + OFF_LHSS);                   // dead lhs_s after makesigT
    float* ps = (float*)(w + OFF_RHSS);                   // dead rhs_s after makesigT
    float* Mf = (float*)(w + OFF_VSBF + 1048576);         // Vsbf dead after GEMM
    float* Inv = (float*)(w + OFF_VSBF + 1048576 + 32768);
    unsigned short* Tx0T = (unsigned short*)(w + OFF_TX0);
    unsigned short* XbfT = (unsigned short*)(w + OFF_XBF);
    unsigned short* sigT = (unsigned short*)(w + OFF_SIGT);
    float* S = (float*)(w + OFF_S);
    unsigned short* Tx1 = (unsigned short*)(w + OFF_S);   // reuse after diag/att extracted
    unsigned short* Tx2 = (unsigned short*)(w + OFF_S + 16777216);

    hipMemsetAsync(w, 0, ZEND, stream);

    // temporal attention (fused X pass; lhs lives only in LDS)
    k_xreduce<<<BB * 64, 256, 0, stream>>>(X, U1, U3, tmp1, rhs);
    k_lhspt<<<BB * 32, 256, 0, stream>>>(tmp1, U2, rhs, Pt);
    k_temporalatt<<<BB, 256, 0, stream>>>(Pt, be, Ve, Emat);

    // spatial attention (Xt computed in-LDS inside k_spatiallr)
    k_spatiallr<<<BB * (NN / 16), 256, 0, stream>>>(X, Emat, W1, W2, W3, lhs_s, rhs_s);
    k_prep<<<NN * NN / 1024, 256, 0, stream>>>(Vs, Vsbf, cW, Wt, Wr, bt, br,
                                               WAcheb, WAtc, WAres, btr);
    k_makesigT<<<dim3(NN / 64, NN / 64), 256, 0, stream>>>(lhs_s, rhs_s, bs, sigT);

    // big GEMM (256² tile, half-tile ring pipeline) + fused column-stat partials
    k_gemm256<<<dim3(NN / 256, NN / 256, BB), 512, 0, stream>>>(Vsbf, sigT, S, pm, ps);
    k_colreduce2<<<BB * NN / 256, 256, 0, stream>>>(pm, ps, Mf, Inv);

    // graph prep (cnt fused into deg; norm fused into scatter)
    k_deg<<<EE / 256, 256, 0, stream>>>(row, col, deg, cnt);
    k_dinv<<<NN / 256, 256, 0, stream>>>(deg, dinv);
    k_scan<<<1, 256, 0, stream>>>(cnt, starts);
    k_scatter<<<EE / 256, 256, 0, stream>>>(row, col, dinv, starts, cursor, eid, normv);
    k_diagatt<<<BB * EE / 256, 256, 0, stream>>>(S, row, col, normv, Mf, Inv, diagS, att);

    // chebyshev (bf16 transposed [t][f] pipeline)
    k_tx0T<<<BB * NN / 4, 256, 0, stream>>>(X, diagS, Tx0T, XbfT);
    k_prop<<<BB * NN / 2, 256, 0, stream>>>(Tx0T, att, col, starts, eid, nullptr, Tx1, 0);
    k_prop<<<BB * NN / 2, 256, 0, stream>>>(Tx1, att, col, starts, eid, Tx0T, Tx2, 1);

    // fused cheb + temporal conv + residual + LN (MFMA, 1 wave / node, direct frag loads)
    k_chebfinal<<<BB * NN, 64, 0, stream>>>(Tx0T, Tx1, Tx2, XbfT,
                                            WAcheb, WAtc, WAres,
                                            cb, btr, gamma, beta, out);
}

// Round 14
// 253.497 us; speedup vs baseline: 1.0190x; 1.0190x over previous
//
#include <hip/hip_runtime.h>
#include <hip/hip_bf16.h>

#define BB 4
#define NN 2048
#define FIN 32
#define TT 16
#define EE 32768
#define CC 64
#define TFo 64
#define NSPLIT 8

typedef __attribute__((ext_vector_type(8))) short bf16x8;
typedef __attribute__((ext_vector_type(4))) float f32x4;

typedef __attribute__((address_space(1))) const unsigned int as1_uint;
typedef __attribute__((address_space(3))) unsigned int as3_uint;

__device__ __forceinline__ void gload_lds16(const void* g, void* l) {
    __builtin_amdgcn_global_load_lds((as1_uint*)g, (as3_uint*)l, 16, 0, 0);
}

__device__ __forceinline__ unsigned short f2bf(float v) {
    unsigned u = __builtin_bit_cast(unsigned, v);
    unsigned r = (u + 0x7fffu + ((u >> 16) & 1u)) >> 16;
    return (unsigned short)r;
}

__device__ __forceinline__ float bf2f(unsigned short v) {
    return __builtin_bit_cast(float, (unsigned)v << 16);
}

// ---------------- Stage A: temporal attention ----------------

__global__ void k_xreduce(const float* __restrict__ X, const float* __restrict__ U1,
                          const float* __restrict__ U3,
                          float* __restrict__ tmp1, float* __restrict__ rhs) {
    int b = blockIdx.x >> 6;
    int n0 = (blockIdx.x & 63) * 32;
    int tid = threadIdx.x;
    int w = tid >> 6, lane = tid & 63;
    float u3a = U3[tid >> 4];
    float u3b = U3[(tid >> 4) + 16];
    __shared__ float part[32][4][16];
    float a0 = 0.f, a1 = 0.f;
    for (int i = 0; i < 32; ++i) {
        int n = n0 + i;
        float u = U1[n];
        const float* rowp = X + ((size_t)(b * NN + n)) * 512;
        float x0 = rowp[tid], x1 = rowp[tid + 256];
        a0 += u * x0; a1 += u * x1;
        float c = u3a * x0 + u3b * x1;
        c += __shfl_xor(c, 16);
        c += __shfl_xor(c, 32);
        if (lane < 16) part[i][w][lane] = c;
    }
    atomicAdd(&tmp1[b * 512 + tid], a0);
    atomicAdd(&tmp1[b * 512 + tid + 256], a1);
    __syncthreads();
#pragma unroll
    for (int q = 0; q < 2; ++q) {
        int idx = tid + q * 256;
        int i = idx >> 4, tt = idx & 15;
        float s = part[i][0][tt] + part[i][1][tt] + part[i][2][tt] + part[i][3][tt];
        rhs[((size_t)(b * NN + n0 + i)) * 16 + tt] = s;
    }
}

// fused mklhs + ptaccum: lhs computed in LDS, never hits HBM (Pt pre-zeroed)
__global__ void k_lhspt(const float* __restrict__ tmp1, const float* __restrict__ U2,
                        const float* __restrict__ rhs, float* __restrict__ Pt) {
    int b = blockIdx.x >> 5;
    int n0 = (blockIdx.x & 31) * 64;
    int tid = threadIdx.x;
    __shared__ float t1[512];
    __shared__ float lhsl[16][65];
    t1[tid] = tmp1[b * 512 + tid];
    t1[tid + 256] = tmp1[b * 512 + tid + 256];
    __syncthreads();
#pragma unroll
    for (int q = 0; q < 4; ++q) {
        int idx = tid + q * 256;
        int t = idx >> 6, nl = idx & 63;
        float acc = 0.f;
#pragma unroll
        for (int f = 0; f < 32; ++f) acc += t1[f * 16 + t] * U2[f * NN + n0 + nl];
        lhsl[t][nl] = acc;
    }
    __syncthreads();
    int t = tid >> 4, s = tid & 15;
    const float* rr = rhs + (size_t)b * NN * TT;
    float acc = 0.f;
    for (int i = 0; i < 64; ++i) acc += lhsl[t][i] * rr[(n0 + i) * 16 + s];
    atomicAdd(&Pt[b * 256 + tid], acc);
}

__global__ void k_temporalatt(const float* __restrict__ Pt, const float* __restrict__ be,
                              const float* __restrict__ Ve, float* __restrict__ Emat) {
    int b = blockIdx.x;
    int t = threadIdx.x >> 4, s = threadIdx.x & 15;
    __shared__ float sg[16][17];
    __shared__ float em[16][17];
    float v = Pt[b * 256 + t * 16 + s] + be[t * 16 + s];
    sg[t][s] = 1.f / (1.f + __expf(-v));
    __syncthreads();
    float e = 0.f;
#pragma unroll
    for (int u = 0; u < 16; ++u) e += Ve[t * 16 + u] * sg[u][s];
    em[t][s] = e;
    __syncthreads();
    float mx = -1e30f;
#pragma unroll
    for (int u = 0; u < 16; ++u) mx = fmaxf(mx, em[u][s]);
    float sum = 0.f;
#pragma unroll
    for (int u = 0; u < 16; ++u) sum += __expf(em[u][s] - mx);
    Emat[b * 256 + t * 16 + s] = __expf(e - mx) / sum;
}

// ---------------- Stage B: spatial attention (applyemat fused in) ----------------

__global__ void k_spatiallr(const float* __restrict__ X, const float* __restrict__ Emat,
                            const float* __restrict__ W1, const float* __restrict__ W2,
                            const float* __restrict__ W3,
                            float* __restrict__ lhs_s, float* __restrict__ rhs_s) {
    int b = blockIdx.x >> 7;
    int n0 = (blockIdx.x & 127) * 16;
    __shared__ float em[256];
    __shared__ float xb[16 * 32 * 17];   // Xt, [(nl*32+f)*17 + s]
    __shared__ float av[16 * 32];
    em[threadIdx.x] = Emat[b * 256 + threadIdx.x];
    __syncthreads();
#pragma unroll
    for (int ii = 0; ii < 2; ++ii) {
        int p = threadIdx.x * 2 + ii;    // nl*32 + f
        int nl = p >> 5, f = p & 31;
        const float4* src = (const float4*)(X + ((size_t)(b * NN + n0 + nl)) * 512 + f * 16);
        float4 q0 = src[0], q1 = src[1], q2 = src[2], q3 = src[3];
        float xv[16] = {q0.x, q0.y, q0.z, q0.w, q1.x, q1.y, q1.z, q1.w,
                        q2.x, q2.y, q2.z, q2.w, q3.x, q3.y, q3.z, q3.w};
        float o[16];
#pragma unroll
        for (int s = 0; s < 16; ++s) o[s] = 0.f;
#pragma unroll
        for (int t = 0; t < 16; ++t) {
            float xt = xv[t];
            const float* er = &em[t * 16];
#pragma unroll
            for (int s = 0; s < 16; ++s) o[s] += xt * er[s];
        }
        float a = 0.f;
#pragma unroll
        for (int s = 0; s < 16; ++s) { xb[p * 17 + s] = o[s]; a += o[s] * W1[s]; }
        av[p] = a;
    }
    __syncthreads();
    int nl = threadIdx.x >> 4, t = threadIdx.x & 15;
    float r = 0.f;
#pragma unroll
    for (int f = 0; f < 32; ++f) r += W3[f] * xb[(nl * 32 + f) * 17 + t];
    rhs_s[(size_t)b * TT * NN + (size_t)t * NN + n0 + nl] = r;
    float l = 0.f;
#pragma unroll
    for (int f = 0; f < 32; ++f) l += av[nl * 32 + f] * W2[f * 16 + t];
    lhs_s[((size_t)(b * NN + n0 + nl)) * 16 + t] = l;
}

// ---------------- fused prep: Vs->bf16 (vectorized) + MFMA A-fragment build ----------
__global__ void k_prep(const float* __restrict__ Vs, unsigned short* __restrict__ Vsbf,
                       const float* __restrict__ cW, const float* __restrict__ Wt,
                       const float* __restrict__ Wr, const float* __restrict__ bt,
                       const float* __restrict__ br,
                       unsigned short* __restrict__ WAcheb,
                       unsigned short* __restrict__ WAtc,
                       unsigned short* __restrict__ WAres,
                       float* __restrict__ btr) {
    int i = blockIdx.x * 256 + threadIdx.x;
    {
        float4 v = *((const float4*)Vs + i);
        ushort4 o;
        o.x = f2bf(v.x); o.y = f2bf(v.y); o.z = f2bf(v.z); o.w = f2bf(v.w);
        *((ushort4*)Vsbf + i) = o;
    }
    int idx = i;
    if (idx < 6144) {                      // cheb
        int j = idx & 7, l = (idx >> 3) & 63, fi = idx >> 9;   // fi = ks*4+i
        int row = ((fi & 3) << 4) + (l & 15);
        int kidx = ((fi >> 2) << 5) + ((l >> 4) << 3) + j;
        int k = kidx >> 5, f = kidx & 31;
        WAcheb[idx] = f2bf(cW[k * 2048 + f * 64 + row]);
    } else if (idx < 18432) {              // temporal conv
        int e = idx - 6144;
        int j = e & 7, l = (e >> 3) & 63, fi = e >> 9;         // fi = ks*4+i, ks<6
        int row = ((fi & 3) << 4) + (l & 15);
        int kidx = ((fi >> 2) << 5) + ((l >> 4) << 3) + j;
        int tap = kidx >> 6, c = kidx & 63;
        WAtc[e] = f2bf(Wt[row * 192 + c * 3 + tap]);
    } else if (idx < 20480) {              // residual
        int e = idx - 18432;
        int j = e & 7, l = (e >> 3) & 63, q = e >> 9;
        int row = (q << 4) + (l & 15);
        int f = ((l >> 4) << 3) + j;
        WAres[e] = f2bf(Wr[row * 32 + f]);
    } else if (idx < 20544) {
        int o = idx - 20480;
        btr[o] = bt[o] + br[o];
    }
}

// sigT[b][k][m] = bf16(sigmoid(dot(lhs_s[b,m,:], rhs_s[b,:,k]) + bs[m,k]))
__global__ void k_makesigT(const float* __restrict__ lhs_s, const float* __restrict__ rhs_s,
                           const float* __restrict__ bs, unsigned short* __restrict__ sigT) {
    int k0 = blockIdx.x * 64, m0 = blockIdx.y * 64;
    __shared__ float lh[64][17];
    __shared__ float rh[16][64];
    __shared__ float bsl[64][65];
    int tid = threadIdx.x;
#pragma unroll
    for (int i = 0; i < 16; ++i) {
        int idx = tid + i * 256;
        int mi = idx >> 6, kj = idx & 63;
        bsl[mi][kj] = bs[(size_t)(m0 + mi) * NN + k0 + kj];
    }
    int ml = tid & 63;
    int kg = (tid >> 6) * 16;
    for (int b = 0; b < BB; ++b) {
        __syncthreads();
#pragma unroll
        for (int i = 0; i < 4; ++i) {
            int idx = tid + i * 256;
            int mi = idx >> 4, t = idx & 15;
            lh[mi][t] = lhs_s[((size_t)(b * NN + m0 + mi)) * 16 + t];
            int tt = idx >> 6, kj = idx & 63;
            rh[tt][kj] = rhs_s[(size_t)b * TT * NN + (size_t)tt * NN + k0 + kj];
        }
        __syncthreads();
        unsigned short* out = sigT + (size_t)b * NN * NN;
#pragma unroll 4
        for (int ki = 0; ki < 16; ++ki) {
            int kl = kg + ki;
            float acc = bsl[ml][kl];
#pragma unroll
            for (int t = 0; t < 16; ++t) acc += lh[ml][t] * rh[t][kl];
            float sgv = 1.f / (1.f + __expf(-acc));
            out[(size_t)(k0 + kl) * NN + m0 + ml] = f2bf(sgv);
        }
    }
}

// ---------------- big GEMM: 256x256 tile, BK=64, 8 waves, counted-vmcnt pipeline ----------
// (round-12 structure: best known, 71 us / 967 TF)
__global__ __launch_bounds__(512, 2) void k_gemm256(const unsigned short* __restrict__ A,
                                                    const unsigned short* __restrict__ Bt,
                                                    float* __restrict__ C,
                                                    float* __restrict__ pm,
                                                    float* __restrict__ ps) {
    __shared__ __align__(16) unsigned short lds[2][2][256 * 64];   // 128 KB
    const int tid = threadIdx.x;
    const int wid = tid >> 6, lane = tid & 63;
    const int wrM = (wid >> 2) << 7;     // 0 / 128
    const int wcN = (wid & 3) << 6;      // 0..192
    const int rl = lane & 15;
    const int kg = (lane >> 4) << 3;     // shorts
    const int sw = (rl & 7) << 3;        // read-side XOR (shorts)
    const int bm = blockIdx.y << 8;
    const int bn = blockIdx.x << 8;
    const int b = blockIdx.z;
    const unsigned short* Bb = Bt + (size_t)b * NN * NN;
    float* Cb = C + (size_t)b * NN * NN;

    const int srow = (wid << 3) + (lane >> 3);                       // row in 64-row group
    const int skel = (((lane & 7) << 3) ^ ((lane >> 3) << 3));       // pre-swizzled k-elem

    f32x4 acc[8][4];
#pragma unroll
    for (int i = 0; i < 8; ++i)
#pragma unroll
        for (int j = 0; j < 4; ++j) acc[i][j] = (f32x4){0.f, 0.f, 0.f, 0.f};

#define STAGE256(buf, kt)                                                          \
    {                                                                              \
        _Pragma("unroll")                                                          \
        for (int q = 0; q < 4; ++q) {                                              \
            int rowA = (q << 6) + srow;                                            \
            gload_lds16(A + (size_t)(bm + rowA) * NN + ((kt) << 6) + skel,         \
                        &lds[buf][0][(q << 12) + (wid << 9)]);                     \
            gload_lds16(Bb + (size_t)(bn + rowA) * NN + ((kt) << 6) + skel,        \
                        &lds[buf][1][(q << 12) + (wid << 9)]);                     \
        }                                                                          \
    }

#define COMPUTE256(buf)                                                            \
    {                                                                              \
        const unsigned short* la = &lds[buf][0][0];                                \
        const unsigned short* lb = &lds[buf][1][0];                                \
        _Pragma("unroll")                                                          \
        for (int ks = 0; ks < 2; ++ks) {                                           \
            bf16x8 af[8], bfr[4];                                                  \
            _Pragma("unroll")                                                      \
            for (int i = 0; i < 8; ++i) {                                          \
                int r = wrM + (i << 4) + rl;                                       \
                af[i] = *(const bf16x8*)(la + (r << 6) + (((ks << 5) + kg) ^ sw)); \
            }                                                                      \
            _Pragma("unroll")                                                      \
            for (int j = 0; j < 4; ++j) {                                          \
                int r = wcN + (j << 4) + rl;                                       \
                bfr[j] = *(const bf16x8*)(lb + (r << 6) + (((ks << 5) + kg) ^ sw)); \
            }                                                                      \
            _Pragma("unroll")                                                      \
            for (int i = 0; i < 8; ++i)                                            \
                _Pragma("unroll")                                                  \
                for (int j = 0; j < 4; ++j)                                        \
                    acc[i][j] = __builtin_amdgcn_mfma_f32_16x16x32_bf16(af[i], bfr[j], acc[i][j], 0, 0, 0); \
        }                                                                          \
    }

    const int NKT = NN >> 6;   // 32
    STAGE256(0, 0)
    STAGE256(1, 1)
    asm volatile("s_waitcnt vmcnt(8)" ::: "memory");
    asm volatile("s_barrier" ::: "memory");
    for (int t = 0; t < NKT; ++t) {
        int cur = t & 1;
        COMPUTE256(cur)
        asm volatile("s_barrier" ::: "memory");   // all reads of buf[cur] done
        if (t + 2 < NKT) {
            STAGE256(cur, t + 2)
            asm volatile("s_waitcnt vmcnt(8)" ::: "memory");  // buf[cur^1] ready
            asm volatile("s_barrier" ::: "memory");
        } else if (t + 1 < NKT) {
            asm volatile("s_waitcnt vmcnt(0)" ::: "memory");
            asm volatile("s_barrier" ::: "memory");
        }
    }
#undef STAGE256
#undef COMPUTE256

    // ---- C write ----
    const int cl = lane & 15, rg = (lane >> 4) << 2;
#pragma unroll
    for (int i = 0; i < 8; ++i)
#pragma unroll
        for (int j = 0; j < 4; ++j) {
            int m0 = bm + wrM + (i << 4) + rg;
            int n0 = bn + wcN + (j << 4) + cl;
#pragma unroll
            for (int r = 0; r < 4; ++r) Cb[(size_t)(m0 + r) * NN + n0] = acc[i][j][r];
        }

    // ---- fused column-softmax partials over this block's 256 rows ----
    float* smax = (float*)&lds[0][0][0];
    float* ssum = smax + 512;
#pragma unroll
    for (int j = 0; j < 4; ++j) {
        float mx = -1e30f;
#pragma unroll
        for (int i = 0; i < 8; ++i)
#pragma unroll
            for (int r = 0; r < 4; ++r) mx = fmaxf(mx, acc[i][j][r]);
        float se = 0.f;
#pragma unroll
        for (int i = 0; i < 8; ++i)
#pragma unroll
            for (int r = 0; r < 4; ++r) se += __expf(acc[i][j][r] - mx);
#pragma unroll
        for (int m = 16; m <= 32; m <<= 1) {
            float omx = __shfl_xor(mx, m);
            float ose = __shfl_xor(se, m);
            float nm = fmaxf(mx, omx);
            se = se * __expf(mx - nm) + ose * __expf(omx - nm);
            mx = nm;
        }
        if (lane < 16) {
            int idx = wcN + (j << 4) + lane;
            smax[((wid >> 2) << 8) + idx] = mx;
            ssum[((wid >> 2) << 8) + idx] = se;
        }
    }
    __syncthreads();
    if (tid < 256) {
        float m0 = smax[tid], m1 = smax[256 + tid];
        float s0 = ssum[tid], s1 = ssum[256 + tid];
        float nm = fmaxf(m0, m1);
        float s = s0 * __expf(m0 - nm) + s1 * __expf(m1 - nm);
        size_t o = ((size_t)(b * NSPLIT + blockIdx.y) * NN) + bn + tid;
        pm[o] = nm;
        ps[o] = s;
    }
}

// combine NSPLIT partials -> Mf[b][k], Inv[b][k]
__global__ void k_colreduce2(const float* __restrict__ pm, const float* __restrict__ ps,
                             float* __restrict__ Mf, float* __restrict__ Inv) {
    int idx = blockIdx.x * 256 + threadIdx.x;
    float M = -1e30f, Ssum = 0.f;
#pragma unroll
    for (int i = 0; i < NSPLIT; ++i) {
        size_t o = ((size_t)((idx >> 11) * NSPLIT + i) * NN) + (idx & (NN - 1));
        float mm = pm[o], sv = ps[o];
        float nm = fmaxf(M, mm);
        Ssum = Ssum * __expf(M - nm) + sv * __expf(mm - nm);
        M = nm;
    }
    Mf[idx] = M;
    Inv[idx] = 1.f / Ssum;
}

// att only (diag moved into k_tx0T)
__global__ void k_att(const float* __restrict__ S, const int* __restrict__ row,
                      const int* __restrict__ col, const float* __restrict__ norm,
                      const float* __restrict__ Mf, const float* __restrict__ Inv,
                      float* __restrict__ att) {
    int idx = blockIdx.x * 256 + threadIdx.x;
    int b = idx >> 15, e = idx & (EE - 1);
    int c = col[e];
    float v = S[(size_t)b * NN * NN + (size_t)row[e] * NN + c];
    att[idx] = norm[e] * __expf(v - Mf[b * NN + c]) * Inv[b * NN + c];
}

// ---------------- graph prep ----------------

__global__ void k_deg(const int* __restrict__ row, const int* __restrict__ col,
                      float* __restrict__ deg, int* __restrict__ cnt) {
    int e = blockIdx.x * 256 + threadIdx.x;
    if (e < EE) {
        int r = row[e];
        if (r != col[e]) atomicAdd(&deg[r], 1.0f);
        atomicAdd(&cnt[r], 1);
    }
}

__global__ void k_dinv(const float* __restrict__ deg, float* __restrict__ dinv) {
    int n = blockIdx.x * 256 + threadIdx.x;
    if (n < NN) {
        float d = deg[n];
        dinv[n] = d > 0.f ? rsqrtf(fmaxf(d, 1e-12f)) : 0.f;
    }
}

__global__ void k_scan(const int* __restrict__ cnt, int* __restrict__ starts) {
    __shared__ int part[256];
    int t = threadIdx.x;
    int loc[8];
    int s = 0;
#pragma unroll
    for (int i = 0; i < 8; ++i) {
        int c = cnt[t * 8 + i];
        loc[i] = s;
        s += c;
    }
    part[t] = s;
    __syncthreads();
    for (int o = 1; o < 256; o <<= 1) {
        int v = (t >= o) ? part[t - o] : 0;
        __syncthreads();
        part[t] += v;
        __syncthreads();
    }
    int pbase = (t > 0) ? part[t - 1] : 0;
#pragma unroll
    for (int i = 0; i < 8; ++i) starts[t * 8 + i] = pbase + loc[i];
    if (t == 255) starts[NN] = part[255];
}

__global__ void k_scatter(const int* __restrict__ row, const int* __restrict__ col,
                          const float* __restrict__ dinv, const int* __restrict__ starts,
                          int* __restrict__ cursor, int* __restrict__ eid,
                          float* __restrict__ norm) {
    int e = blockIdx.x * 256 + threadIdx.x;
    if (e < EE) {
        int r = row[e], c = col[e];
        float w = (r != c) ? 1.f : 0.f;
        norm[e] = -dinv[r] * w * dinv[c];
        int slot = atomicAdd(&cursor[r], 1);
        eid[starts[r] + slot] = e;
    }
}

// ---------------- Chebyshev (bf16 TRANSPOSED [t][f] pipeline) ----------------

// diagS computed inline from S diag + col stats; Tx0T/XbfT written [t][f] bf16
__global__ void k_tx0T(const float* __restrict__ X, const float* __restrict__ S,
                       const float* __restrict__ Mf, const float* __restrict__ Inv,
                       unsigned short* __restrict__ Tx0T, unsigned short* __restrict__ XbfT) {
    int j = threadIdx.x >> 6, l = threadIdx.x & 63;
    int bn = (blockIdx.x << 2) + j;
    int b = bn >> 11, n = bn & (NN - 1);
    __shared__ float lt[4][16][33];
    float sv = S[(size_t)b * NN * NN + (size_t)n * NN + n];   // wave-uniform broadcast
    float d = __expf(sv - Mf[bn]) * Inv[bn];
    const float* xp = X + (size_t)bn * 512;
    {
        int f = l >> 1, t0 = (l & 1) << 3;
        float4 a = *(const float4*)(xp + f * 16 + t0);
        float4 b4 = *(const float4*)(xp + f * 16 + t0 + 4);
        lt[j][t0 + 0][f] = a.x;  lt[j][t0 + 1][f] = a.y;
        lt[j][t0 + 2][f] = a.z;  lt[j][t0 + 3][f] = a.w;
        lt[j][t0 + 4][f] = b4.x; lt[j][t0 + 5][f] = b4.y;
        lt[j][t0 + 6][f] = b4.z; lt[j][t0 + 7][f] = b4.w;
    }
    __syncthreads();
    int t = l >> 2, f0 = (l & 3) << 3;
    unsigned ox[4], otx[4];
#pragma unroll
    for (int i = 0; i < 4; ++i) {
        float v0 = lt[j][t][f0 + 2 * i];
        float v1 = lt[j][t][f0 + 2 * i + 1];
        ox[i] = (unsigned)f2bf(v0) | ((unsigned)f2bf(v1) << 16);
        otx[i] = (unsigned)f2bf(v0 * d) | ((unsigned)f2bf(v1 * d) << 16);
    }
    size_t o = (size_t)bn * 512 + t * 32 + f0;
    *(uint4*)(XbfT + o) = make_uint4(ox[0], ox[1], ox[2], ox[3]);
    *(uint4*)(Tx0T + o) = make_uint4(otx[0], otx[1], otx[2], otx[3]);
}

__global__ void k_prop(const unsigned short* __restrict__ x, const float* __restrict__ att,
                       const int* __restrict__ col, const int* __restrict__ starts,
                       const int* __restrict__ eid, const unsigned short* __restrict__ sub,
                       unsigned short* __restrict__ out, int mode) {
    int g = threadIdx.x >> 7;
    int l = threadIdx.x & 127;
    int bn = (blockIdx.x << 1) + g;
    int b = bn >> 11, n = bn & (NN - 1);
    int s0 = starts[n], s1 = starts[n + 1];
    const unsigned short* xb = x + (size_t)b * NN * 512;
    const float* attb = att + (size_t)b * EE;
    float ax = 0.f, ay = 0.f, az = 0.f, aw = 0.f;
    float bx = 0.f, by = 0.f, bz = 0.f, bw = 0.f;
    int jj = s0;
    for (; jj + 2 <= s1; jj += 2) {
        int e0 = eid[jj], e1 = eid[jj + 1];
        float a0 = attb[e0], a1 = attb[e1];
        ushort4 v0 = *((const ushort4*)(xb + (size_t)col[e0] * 512) + l);
        ushort4 v1 = *((const ushort4*)(xb + (size_t)col[e1] * 512) + l);
        ax += a0 * bf2f(v0.x); ay += a0 * bf2f(v0.y); az += a0 * bf2f(v0.z); aw += a0 * bf2f(v0.w);
        bx += a1 * bf2f(v1.x); by += a1 * bf2f(v1.y); bz += a1 * bf2f(v1.z); bw += a1 * bf2f(v1.w);
    }
    if (jj < s1) {
        int e0 = eid[jj];
        float a0 = attb[e0];
        ushort4 v0 = *((const ushort4*)(xb + (size_t)col[e0] * 512) + l);
        ax += a0 * bf2f(v0.x); ay += a0 * bf2f(v0.y); az += a0 * bf2f(v0.z); aw += a0 * bf2f(v0.w);
    }
    float rx = ax + bx, ry = ay + by, rz = az + bz, rw = aw + bw;
    size_t o = (size_t)bn * 512 + (l << 2);
    if (mode) {
        ushort4 sv = *(const ushort4*)(sub + o);
        rx = 2.f * rx - bf2f(sv.x); ry = 2.f * ry - bf2f(sv.y);
        rz = 2.f * rz - bf2f(sv.z); rw = 2.f * rw - bf2f(sv.w);
    }
    ushort4 ov;
    ov.x = f2bf(rx); ov.y = f2bf(ry); ov.z = f2bf(rz); ov.w = f2bf(rw);
    *(ushort4*)(out + o) = ov;
}

// ---------------- fused cheb + temporal conv + residual + LN via MFMA ----------------
#define XHP2 72
__global__ __launch_bounds__(64) void k_chebfinal(
    const unsigned short* __restrict__ Tx0T, const unsigned short* __restrict__ Tx1T,
    const unsigned short* __restrict__ Tx2T, const unsigned short* __restrict__ XbfT,
    const unsigned short* __restrict__ WAcheb,
    const unsigned short* __restrict__ WAtc,
    const unsigned short* __restrict__ WAres,
    const float* __restrict__ cb, const float* __restrict__ btr,
    const float* __restrict__ gamma, const float* __restrict__ beta,
    float* __restrict__ out) {
    int l = threadIdx.x;
    int bn = blockIdx.x;
    int tl = l & 15, fg = l >> 4;
    __shared__ unsigned short xhT[18 * XHP2];
    xhT[l] = 0;
    xhT[17 * XHP2 + l] = 0;
    size_t fo = (size_t)bn * 512 + tl * 32 + fg * 8;
    bf16x8 bT0 = *(const bf16x8*)(Tx0T + fo);
    bf16x8 bT1 = *(const bf16x8*)(Tx1T + fo);
    bf16x8 bT2 = *(const bf16x8*)(Tx2T + fo);
    bf16x8 bX = *(const bf16x8*)(XbfT + fo);

    // --- cheb ---
    f32x4 acc[4];
#pragma unroll
    for (int i = 0; i < 4; ++i) acc[i] = (f32x4){0.f, 0.f, 0.f, 0.f};
#pragma unroll
    for (int ks = 0; ks < 3; ++ks) {
        bf16x8 bfrag = (ks == 0) ? bT0 : (ks == 1) ? bT1 : bT2;
#pragma unroll
        for (int i = 0; i < 4; ++i)
            acc[i] = __builtin_amdgcn_mfma_f32_16x16x32_bf16(
                *(const bf16x8*)&WAcheb[((ks * 4 + i) * 64 + l) * 8], bfrag, acc[i], 0, 0, 0);
    }
#pragma unroll
    for (int i = 0; i < 4; ++i) {
        int cbase = i * 16 + fg * 4;
        float4 cv = *(const float4*)&cb[cbase];
        float h0 = fmaxf(acc[i][0] + cv.x, 0.f);
        float h1 = fmaxf(acc[i][1] + cv.y, 0.f);
        float h2v = fmaxf(acc[i][2] + cv.z, 0.f);
        float h3 = fmaxf(acc[i][3] + cv.w, 0.f);
        unsigned lo = (unsigned)f2bf(h0) | ((unsigned)f2bf(h1) << 16);
        unsigned hi = (unsigned)f2bf(h2v) | ((unsigned)f2bf(h3) << 16);
        *(uint2*)&xhT[(tl + 1) * XHP2 + cbase] = make_uint2(lo, hi);
    }
    __syncthreads();

    // --- temporal conv + residual ---
    f32x4 a2[4];
#pragma unroll
    for (int i = 0; i < 4; ++i) a2[i] = (f32x4){0.f, 0.f, 0.f, 0.f};
#pragma unroll
    for (int ks = 0; ks < 6; ++ks) {
        int kb = ks * 32 + fg * 8;
        bf16x8 bfrag = *(const bf16x8*)&xhT[(tl + (kb >> 6)) * XHP2 + (kb & 63)];
#pragma unroll
        for (int i = 0; i < 4; ++i)
            a2[i] = __builtin_amdgcn_mfma_f32_16x16x32_bf16(
                *(const bf16x8*)&WAtc[((ks * 4 + i) * 64 + l) * 8], bfrag, a2[i], 0, 0, 0);
    }
#pragma unroll
    for (int i = 0; i < 4; ++i)
        a2[i] = __builtin_amdgcn_mfma_f32_16x16x32_bf16(
            *(const bf16x8*)&WAres[(i * 64 + l) * 8], bX, a2[i], 0, 0, 0);

    float h2[16];
#pragma unroll
    for (int i = 0; i < 4; ++i) {
        float4 bv = *(const float4*)&btr[i * 16 + fg * 4];
        h2[i * 4 + 0] = fmaxf(a2[i][0] + bv.x, 0.f);
        h2[i * 4 + 1] = fmaxf(a2[i][1] + bv.y, 0.f);
        h2[i * 4 + 2] = fmaxf(a2[i][2] + bv.z, 0.f);
        h2[i * 4 + 3] = fmaxf(a2[i][3] + bv.w, 0.f);
    }
    float s1 = 0.f, s2 = 0.f;
#pragma unroll
    for (int q = 0; q < 16; ++q) { s1 += h2[q]; s2 += h2[q] * h2[q]; }
    s1 += __shfl_xor(s1, 16); s2 += __shfl_xor(s2, 16);
    s1 += __shfl_xor(s1, 32); s2 += __shfl_xor(s2, 32);
    float mu = s1 * (1.f / 64.f);
    float rs = rsqrtf(s2 * (1.f / 64.f) - mu * mu + 1e-5f);
    float* ob = out + (size_t)bn * 1024 + tl;
#pragma unroll
    for (int i = 0; i < 4; ++i) {
        int cbase = i * 16 + fg * 4;
        float4 gv = *(const float4*)&gamma[cbase];
        float4 bv = *(const float4*)&beta[cbase];
        ob[(cbase + 0) * 16] = (h2[i * 4 + 0] - mu) * rs * gv.x + bv.x;
        ob[(cbase + 1) * 16] = (h2[i * 4 + 1] - mu) * rs * gv.y + bv.y;
        ob[(cbase + 2) * 16] = (h2[i * 4 + 2] - mu) * rs * gv.z + bv.z;
        ob[(cbase + 3) * 16] = (h2[i * 4 + 3] - mu) * rs * gv.w + bv.w;
    }
}

// ---------------- host ----------------

extern "C" void kernel_launch(void* const* d_in, const int* in_sizes, int n_in,
                              void* d_out, int out_size, void* d_ws, size_t ws_size,
                              hipStream_t stream) {
    (void)in_sizes; (void)n_in; (void)out_size; (void)ws_size;
    const float* X = (const float*)d_in[0];
    const int* ei = (const int*)d_in[1];
    const int* row = ei;
    const int* col = ei + EE;
    const float* U1 = (const float*)d_in[2];
    const float* U2 = (const float*)d_in[3];
    const float* U3 = (const float*)d_in[4];
    const float* be = (const float*)d_in[5];
    const float* Ve = (const float*)d_in[6];
    const float* W1 = (const float*)d_in[7];
    const float* W2 = (const float*)d_in[8];
    const float* W3 = (const float*)d_in[9];
    const float* bs = (const float*)d_in[10];
    const float* Vs = (const float*)d_in[11];
    const float* cW = (const float*)d_in[12];
    const float* cb = (const float*)d_in[13];
    const float* Wt = (const float*)d_in[14];
    const float* bt = (const float*)d_in[15];
    const float* Wr = (const float*)d_in[16];
    const float* br = (const float*)d_in[17];
    const float* gamma = (const float*)d_in[18];
    const float* beta = (const float*)d_in[19];
    float* out = (float*)d_out;

    char* w = (char*)d_ws;
    constexpr size_t OFF_TMP1 = 0;            // 8192
    constexpr size_t OFF_PT = 8192;           // 4096
    constexpr size_t OFF_DEG = 12288;         // 8192
    constexpr size_t OFF_CNT = 20480;         // 8192
    constexpr size_t OFF_CURSOR = 28672;      // 8192
    constexpr size_t ZEND = 36864;
    constexpr size_t OFF_EMAT = ZEND;                     // 4096
    constexpr size_t OFF_LHS = OFF_EMAT + 4096;           // 512K (unused)
    constexpr size_t OFF_RHS = OFF_LHS + 524288;          // 512K
    constexpr size_t OFF_LHSS = OFF_RHS + 524288;         // 512K (reused: pm)
    constexpr size_t OFF_RHSS = OFF_LHSS + 524288;        // 512K (reused: ps)
    constexpr size_t OFF_DIAG = OFF_RHSS + 524288;        // 32K (unused)
    constexpr size_t OFF_ATT = OFF_DIAG + 32768;          // 512K
    constexpr size_t OFF_DINV = OFF_ATT + 524288;         // 8K
    constexpr size_t OFF_NORM = OFF_DINV + 8192;          // 128K
    constexpr size_t OFF_STARTS = OFF_NORM + 131072;      // 8448
    constexpr size_t OFF_EID = OFF_STARTS + 8448;         // 128K
    constexpr size_t OFF_WA = OFF_EID + 131072;           // 56K region for frags
    constexpr size_t OFF_WACHEB = OFF_WA;                 // 12288
    constexpr size_t OFF_WATC = OFF_WA + 12288;           // 24576
    constexpr size_t OFF_WARES = OFF_WA + 36864;          // 4096
    constexpr size_t OFF_BTR = OFF_WA + 40960;            // 256
    constexpr size_t OFF_VSBF = OFF_WA + 57344;           // 8MB (reused: Mf/Inv)
    constexpr size_t OFF_TX0 = OFF_VSBF + 8388608;        // 8.4MB Tx0T + 8.4MB XbfT
    constexpr size_t OFF_XBF = OFF_TX0 + 8388608;
    constexpr size_t OFF_SIGT = OFF_XBF + 8388608;        // 32MB
    constexpr size_t OFF_S = OFF_SIGT + 33554432;         // 64MB (reused: Tx1, Tx2 bf16)

    float* tmp1 = (float*)(w + OFF_TMP1);
    float* Pt = (float*)(w + OFF_PT);
    float* deg = (float*)(w + OFF_DEG);
    int* cnt = (int*)(w + OFF_CNT);
    int* cursor = (int*)(w + OFF_CURSOR);
    float* Emat = (float*)(w + OFF_EMAT);
    float* rhs = (float*)(w + OFF_RHS);
    float* lhs_s = (float*)(w + OFF_LHSS);
    float* rhs_s = (float*)(w + OFF_RHSS);
    float* att = (float*)(w + OFF_ATT);
    float* dinv = (float*)(w + OFF_DINV);
    float* normv = (float*)(w + OFF_NORM);
    int* starts = (int*)(w + OFF_STARTS);
    int* eid = (int*)(w + OFF_EID);
    unsigned short* WAcheb = (unsigned short*)(w + OFF_WACHEB);
    unsigned short* WAtc = (unsigned short*)(w + OFF_WATC);
    unsigned short* WAres = (unsigned short*)(w + OFF_WARES);
    float* btr = (float*)(w + OFF_BTR);
    unsigned short* Vsbf = (unsigned short*)(w + OFF_VSBF);
    float* pm = (float*)(w + OFF_LHSS);                   // dead lhs_s after makesigT
    float* ps = (float*)(w + OFF_RHSS);                   // dead rhs_s after makesigT
    float* Mf = (float*)(w + OFF_VSBF + 1048576);         // Vsbf dead after GEMM
    float* Inv = (float*)(w + OFF_VSBF + 1048576 + 32768);
    unsigned short* Tx0T = (unsigned short*)(w + OFF_TX0);
    unsigned short* XbfT = (unsigned short*)(w + OFF_XBF);
    unsigned short* sigT = (unsigned short*)(w + OFF_SIGT);
    float* S = (float*)(w + OFF_S);
    unsigned short* Tx1 = (unsigned short*)(w + OFF_S);   // reuse after att extracted
    unsigned short* Tx2 = (unsigned short*)(w + OFF_S + 16777216);

    hipMemsetAsync(w, 0, ZEND, stream);

    // temporal attention (fused X pass; lhs lives only in LDS)
    k_xreduce<<<BB * 64, 256, 0, stream>>>(X, U1, U3, tmp1, rhs);
    k_lhspt<<<BB * 32, 256, 0, stream>>>(tmp1, U2, rhs, Pt);
    k_temporalatt<<<BB, 256, 0, stream>>>(Pt, be, Ve, Emat);

    // spatial attention (Xt computed in-LDS inside k_spatiallr)
    k_spatiallr<<<BB * (NN / 16), 256, 0, stream>>>(X, Emat, W1, W2, W3, lhs_s, rhs_s);
    k_prep<<<NN * NN / 1024, 256, 0, stream>>>(Vs, Vsbf, cW, Wt, Wr, bt, br,
                                               WAcheb, WAtc, WAres, btr);
    k_makesigT<<<dim3(NN / 64, NN / 64), 256, 0, stream>>>(lhs_s, rhs_s, bs, sigT);

    // big GEMM (256² tile, counted-vmcnt pipeline) + fused column-stat partials
    k_gemm256<<<dim3(NN / 256, NN / 256, BB), 512, 0, stream>>>(Vsbf, sigT, S, pm, ps);
    k_colreduce2<<<BB * NN / 256, 256, 0, stream>>>(pm, ps, Mf, Inv);

    // graph prep (cnt fused into deg; norm fused into scatter)
    k_deg<<<EE / 256, 256, 0, stream>>>(row, col, deg, cnt);
    k_dinv<<<NN / 256, 256, 0, stream>>>(deg, dinv);
    k_scan<<<1, 256, 0, stream>>>(cnt, starts);
    k_scatter<<<EE / 256, 256, 0, stream>>>(row, col, dinv, starts, cursor, eid, normv);
    k_att<<<BB * EE / 256, 256, 0, stream>>>(S, row, col, normv, Mf, Inv, att);

    // chebyshev (bf16 transposed [t][f] pipeline; diagS computed inline)
    k_tx0T<<<BB * NN / 4, 256, 0, stream>>>(X, S, Mf, Inv, Tx0T, XbfT);
    k_prop<<<BB * NN / 2, 256, 0, stream>>>(Tx0T, att, col, starts, eid, nullptr, Tx1, 0);
    k_prop<<<BB * NN / 2, 256, 0, stream>>>(Tx1, att, col, starts, eid, Tx0T, Tx2, 1);

    // fused cheb + temporal conv + residual + LN (MFMA, 1 wave / node, direct frag loads)
    k_chebfinal<<<BB * NN, 64, 0, stream>>>(Tx0T, Tx1, Tx2, XbfT,
                                            WAcheb, WAtc, WAres,
                                            cb, btr, gamma, beta, out);
}